// Round 10
// baseline (229.715 us; speedup 1.0000x reference)
//
#include <hip/hip_runtime.h>
#include <hip/hip_bf16.h>
#include <math.h>

// Problem constants (B=4, C=64, H=W=L=16)
#define BATCH 4
#define CH    64
#define NVOX  4096
#define NGRP  32
#define EPS   1e-5f

typedef float f32x4 __attribute__((ext_vector_type(4)));
typedef short s16x8 __attribute__((ext_vector_type(8)));

static __device__ inline unsigned short f2bf(float f) {
    union { __hip_bfloat16 h; unsigned short u; } cv;
    cv.h = __float2bfloat16(f);
    return cv.u;
}

// ---------------------------------------------------------------------------
// Kernel 1: GroupNorm statistics. One block per (b, g): 8192 elements.
// ---------------------------------------------------------------------------
__global__ __launch_bounds__(256) void k_gnstats(const float* __restrict__ x,
                                                 float* __restrict__ stats) {
    int bg = blockIdx.x;                       // b*32 + g
    const float4* p4 = (const float4*)(x + (size_t)bg * (2 * NVOX));
    float s = 0.f, sq = 0.f;
    for (int i = threadIdx.x; i < (2 * NVOX) / 4; i += 256) {
        float4 v = p4[i];
        s  += v.x + v.y + v.z + v.w;
        sq += v.x * v.x + v.y * v.y + v.z * v.z + v.w * v.w;
    }
    for (int off = 32; off; off >>= 1) {
        s  += __shfl_down(s, off);
        sq += __shfl_down(sq, off);
    }
    __shared__ float ls[4], lq[4];
    int wid = threadIdx.x >> 6;
    if ((threadIdx.x & 63) == 0) { ls[wid] = s; lq[wid] = sq; }
    __syncthreads();
    if (threadIdx.x == 0) {
        s  = ls[0] + ls[1] + ls[2] + ls[3];
        sq = lq[0] + lq[1] + lq[2] + lq[3];
        float mean = s / (float)(2 * NVOX);
        float var  = sq / (float)(2 * NVOX) - mean * mean;
        stats[bg]       = mean;
        stats[128 + bg] = rsqrtf(var + EPS);
    }
}

// ---------------------------------------------------------------------------
// Kernel 2: fused normalize + QKV projection. Outputs bf16:
//   Qb [B][N][64]  (pre-scaled by 1/sqrt(C)=0.125)
//   Kb [B][N][64]
//   Vb [B][64][N]
// ---------------------------------------------------------------------------
__global__ __launch_bounds__(256) void k_qkv(const float* __restrict__ x,
                                             const float* __restrict__ stats,
                                             const float* __restrict__ gw,
                                             const float* __restrict__ gb,
                                             const float* __restrict__ W,
                                             unsigned short* __restrict__ Qb,
                                             unsigned short* __restrict__ Kb,
                                             unsigned short* __restrict__ Vb) {
    int b  = blockIdx.x >> 6;
    int n0 = (blockIdx.x & 63) * 64;
    int t  = threadIdx.x;
    __shared__ float nm[64][64];                 // [c][n]
    __shared__ alignas(16) unsigned short tb[64][72];  // [n][d] transpose buf

    for (int i = t; i < 64 * 16; i += 256) {
        int c = i >> 4;
        int n = (i & 15) * 4;
        float4 v = *(const float4*)&x[((size_t)(b * CH + c)) * NVOX + n0 + n];
        float mean = stats[b * NGRP + (c >> 1)];
        float rstd = stats[128 + b * NGRP + (c >> 1)];
        float sc = rstd * gw[c];
        float sh = gb[c] - mean * sc;
        nm[c][n + 0] = v.x * sc + sh;
        nm[c][n + 1] = v.y * sc + sh;
        nm[c][n + 2] = v.z * sc + sh;
        nm[c][n + 3] = v.w * sc + sh;
    }
    __syncthreads();

    int nl = t & 63;
    int dg = t >> 6;
    float r[64];
    #pragma unroll
    for (int c = 0; c < 64; ++c) r[c] = nm[c][nl];

    // ---- Q round (rows 0..63 of W), scaled by 0.125 ----
    #pragma unroll 4
    for (int j = 0; j < 16; ++j) {
        int d = dg * 16 + j;
        const float* w = &W[d * 64];
        float acc = 0.f;
        #pragma unroll
        for (int c = 0; c < 64; ++c) acc += w[c] * r[c];
        tb[nl][d] = f2bf(acc * 0.125f);
    }
    __syncthreads();
    {
        int n = t >> 2, d0 = (t & 3) * 16;
        s16x8 a0 = *(const s16x8*)&tb[n][d0];
        s16x8 a1 = *(const s16x8*)&tb[n][d0 + 8];
        size_t base = ((size_t)(b * NVOX + n0 + n)) * 64 + d0;
        *(s16x8*)&Qb[base]     = a0;
        *(s16x8*)&Qb[base + 8] = a1;
    }
    __syncthreads();

    // ---- K round (rows 64..127) ----
    #pragma unroll 4
    for (int j = 0; j < 16; ++j) {
        int d = dg * 16 + j;
        const float* w = &W[(64 + d) * 64];
        float acc = 0.f;
        #pragma unroll
        for (int c = 0; c < 64; ++c) acc += w[c] * r[c];
        tb[nl][d] = f2bf(acc);
    }
    __syncthreads();
    {
        int n = t >> 2, d0 = (t & 3) * 16;
        s16x8 a0 = *(const s16x8*)&tb[n][d0];
        s16x8 a1 = *(const s16x8*)&tb[n][d0 + 8];
        size_t base = ((size_t)(b * NVOX + n0 + n)) * 64 + d0;
        *(s16x8*)&Kb[base]     = a0;
        *(s16x8*)&Kb[base + 8] = a1;
    }

    // ---- V round (rows 128..191), c-major output ----
    #pragma unroll 4
    for (int j = 0; j < 16; ++j) {
        int d = dg * 16 + j;
        const float* w = &W[(128 + d) * 64];
        float acc = 0.f;
        #pragma unroll
        for (int c = 0; c < 64; ++c) acc += w[c] * r[c];
        Vb[((size_t)(b * 64 + d)) * NVOX + n0 + nl] = f2bf(acc);
    }
}

// ---------------------------------------------------------------------------
// Kernel 3: fused flash attention + combine + out-projection + residual.
// Grid: 1024 blocks = (b, 16-q tile), XCD-swizzled. 4 waves; wave w owns
// KV range [w*1024, (w+1)*1024) with independent online softmax (m,l,acc):
// NO __syncthreads in the main loop. K/V fragments read straight from
// global (L2-resident); only the per-wave Ps transpose uses LDS.
// Epilogue: LDS combine of the 4 per-wave partials, then 64x64 projection
// + bias + residual, written directly to out.
// ---------------------------------------------------------------------------
__global__ __launch_bounds__(256) void k_attn_fused(const unsigned short* __restrict__ Qb,
                                                    const unsigned short* __restrict__ Kb,
                                                    const unsigned short* __restrict__ Vb,
                                                    const float* __restrict__ Wout,
                                                    const float* __restrict__ obias,
                                                    const float* __restrict__ x,
                                                    float* __restrict__ out) {
    // XCD-aware chunked swizzle (1024 % 8 == 0 -> bijective): each XCD's
    // blocks stay within ~1 batch so its L2 caches that batch's K/V.
    int bid = blockIdx.x;
    int swz = (bid & 7) * 128 + (bid >> 3);
    int b   = swz >> 8;            // batch
    int q0  = (swz & 255) * 16;    // q-tile of 16

    int t    = threadIdx.x;
    int lane = t & 63;
    int w    = t >> 6;             // wave id -> KV quarter
    int l15  = lane & 15;
    int g4   = lane >> 4;          // 0..3
    int csl  = g4 * 8;

    __shared__ alignas(16) unsigned short Ps[4][16][72];  // per-wave P transpose
    __shared__ float Part[4][16][68];                     // per-wave partial O
    __shared__ float ml[4][2][16];                        // per-wave m,l
    __shared__ float Os[16][68];                          // combined O

    const unsigned short* Qp = Qb + (size_t)b * NVOX * 64;
    const unsigned short* Kp = Kb + (size_t)b * NVOX * 64;
    const unsigned short* Vp = Vb + (size_t)b * 64 * NVOX;

    // Q fragments (same for all 4 waves): row q = l15, c-slice by g4
    s16x8 qf0 = *(const s16x8*)&Qp[(size_t)(q0 + l15) * 64 + csl];
    s16x8 qf1 = *(const s16x8*)&Qp[(size_t)(q0 + l15) * 64 + csl + 32];

    f32x4 acc_o[4] = {};           // [c-tile][reg], rows q = g4*4+reg
    float m_r[4], l_r[4];
    #pragma unroll
    for (int i = 0; i < 4; ++i) { m_r[i] = -1e30f; l_r[i] = 0.f; }

    const int kvbase = w * (NVOX / 4);

    for (int it = 0; it < (NVOX / 4) / 64; ++it) {
        int kv0 = kvbase + it * 64;

        // ---- S = Q K^T : K fragments straight from global ----
        f32x4 sacc[4];
        #pragma unroll
        for (int kt = 0; kt < 4; ++kt) {
            s16x8 kf0 = *(const s16x8*)&Kp[(size_t)(kv0 + kt * 16 + l15) * 64 + csl];
            s16x8 kf1 = *(const s16x8*)&Kp[(size_t)(kv0 + kt * 16 + l15) * 64 + csl + 32];
            f32x4 z = {0.f, 0.f, 0.f, 0.f};
            sacc[kt] = __builtin_amdgcn_mfma_f32_16x16x32_bf16(qf0, kf0, z, 0, 0, 0);
            sacc[kt] = __builtin_amdgcn_mfma_f32_16x16x32_bf16(qf1, kf1, sacc[kt], 0, 0, 0);
        }

        // ---- online softmax (rows q = g4*4 + reg), wave-parallel ----
        float al[4];
        #pragma unroll
        for (int reg = 0; reg < 4; ++reg) {
            float rmax = fmaxf(fmaxf(sacc[0][reg], sacc[1][reg]),
                               fmaxf(sacc[2][reg], sacc[3][reg]));
            rmax = fmaxf(rmax, __shfl_xor(rmax, 1));
            rmax = fmaxf(rmax, __shfl_xor(rmax, 2));
            rmax = fmaxf(rmax, __shfl_xor(rmax, 4));
            rmax = fmaxf(rmax, __shfl_xor(rmax, 8));
            float mn = fmaxf(m_r[reg], rmax);
            al[reg] = __expf(m_r[reg] - mn);
            m_r[reg] = mn;
        }
        float p[4][4];   // [kt][reg]
        #pragma unroll
        for (int kt = 0; kt < 4; ++kt)
            #pragma unroll
            for (int reg = 0; reg < 4; ++reg)
                p[kt][reg] = __expf(sacc[kt][reg] - m_r[reg]);
        #pragma unroll
        for (int reg = 0; reg < 4; ++reg) {
            float rs = p[0][reg] + p[1][reg] + p[2][reg] + p[3][reg];
            rs += __shfl_xor(rs, 1);
            rs += __shfl_xor(rs, 2);
            rs += __shfl_xor(rs, 4);
            rs += __shfl_xor(rs, 8);
            l_r[reg] = l_r[reg] * al[reg] + rs;
        }
        // P transpose via per-wave LDS (in-wave write->read, no barrier)
        #pragma unroll
        for (int kt = 0; kt < 4; ++kt)
            #pragma unroll
            for (int reg = 0; reg < 4; ++reg)
                Ps[w][g4 * 4 + reg][kt * 16 + l15] = f2bf(p[kt][reg]);
        // rescale O accumulator
        #pragma unroll
        for (int ct = 0; ct < 4; ++ct)
            #pragma unroll
            for (int reg = 0; reg < 4; ++reg)
                acc_o[ct][reg] *= al[reg];

        // ---- PV: A = P frag, B = V fragments straight from global ----
        s16x8 pf0 = *(const s16x8*)&Ps[w][l15][csl];
        s16x8 pf1 = *(const s16x8*)&Ps[w][l15][csl + 32];
        #pragma unroll
        for (int ct = 0; ct < 4; ++ct) {
            s16x8 vf0 = *(const s16x8*)&Vp[(size_t)(ct * 16 + l15) * NVOX + kv0 + csl];
            s16x8 vf1 = *(const s16x8*)&Vp[(size_t)(ct * 16 + l15) * NVOX + kv0 + csl + 32];
            acc_o[ct] = __builtin_amdgcn_mfma_f32_16x16x32_bf16(pf0, vf0, acc_o[ct], 0, 0, 0);
            acc_o[ct] = __builtin_amdgcn_mfma_f32_16x16x32_bf16(pf1, vf1, acc_o[ct], 0, 0, 0);
        }
    }

    // ---- write per-wave partials + stats to LDS ----
    #pragma unroll
    for (int ct = 0; ct < 4; ++ct)
        #pragma unroll
        for (int reg = 0; reg < 4; ++reg)
            Part[w][g4 * 4 + reg][ct * 16 + l15] = acc_o[ct][reg];
    if (l15 == 0) {
        #pragma unroll
        for (int reg = 0; reg < 4; ++reg) {
            ml[w][0][g4 * 4 + reg] = m_r[reg];
            ml[w][1][g4 * 4 + reg] = l_r[reg];
        }
    }
    __syncthreads();

    // ---- combine 4 partials: Os[q][c] normalized ----
    {
        int q  = t & 15;
        int cg = t >> 4;     // 0..15 -> 4 channels
        float m0 = ml[0][0][q], m1 = ml[1][0][q], m2 = ml[2][0][q], m3 = ml[3][0][q];
        float mm = fmaxf(fmaxf(m0, m1), fmaxf(m2, m3));
        float s0 = __expf(m0 - mm), s1 = __expf(m1 - mm);
        float s2 = __expf(m2 - mm), s3 = __expf(m3 - mm);
        float lsum = s0 * ml[0][1][q] + s1 * ml[1][1][q] +
                     s2 * ml[2][1][q] + s3 * ml[3][1][q];
        float inv = 1.f / lsum;
        float4 o0 = *(const float4*)&Part[0][q][cg * 4];
        float4 o1 = *(const float4*)&Part[1][q][cg * 4];
        float4 o2 = *(const float4*)&Part[2][q][cg * 4];
        float4 o3 = *(const float4*)&Part[3][q][cg * 4];
        float4 o;
        o.x = (s0 * o0.x + s1 * o1.x + s2 * o2.x + s3 * o3.x) * inv;
        o.y = (s0 * o0.y + s1 * o1.y + s2 * o2.y + s3 * o3.y) * inv;
        o.z = (s0 * o0.z + s1 * o1.z + s2 * o2.z + s3 * o3.z) * inv;
        o.w = (s0 * o0.w + s1 * o1.w + s2 * o2.w + s3 * o3.w) * inv;
        *(float4*)&Os[q][cg * 4] = o;
    }
    __syncthreads();

    // ---- out projection + bias + residual ----
    {
        int q  = t & 15;
        int dg = t >> 4;     // 0..15 -> 4 output channels
        int n  = q0 + q;
        float a0 = obias[dg * 4 + 0], a1 = obias[dg * 4 + 1];
        float a2 = obias[dg * 4 + 2], a3 = obias[dg * 4 + 3];
        #pragma unroll
        for (int c4 = 0; c4 < 16; ++c4) {
            float4 ov = *(const float4*)&Os[q][c4 * 4];
            float4 w0 = *(const float4*)&Wout[(size_t)(dg * 4 + 0) * 64 + c4 * 4];
            float4 w1 = *(const float4*)&Wout[(size_t)(dg * 4 + 1) * 64 + c4 * 4];
            float4 w2 = *(const float4*)&Wout[(size_t)(dg * 4 + 2) * 64 + c4 * 4];
            float4 w3 = *(const float4*)&Wout[(size_t)(dg * 4 + 3) * 64 + c4 * 4];
            a0 += w0.x * ov.x + w0.y * ov.y + w0.z * ov.z + w0.w * ov.w;
            a1 += w1.x * ov.x + w1.y * ov.y + w1.z * ov.z + w1.w * ov.w;
            a2 += w2.x * ov.x + w2.y * ov.y + w2.z * ov.z + w2.w * ov.w;
            a3 += w3.x * ov.x + w3.y * ov.y + w3.z * ov.z + w3.w * ov.w;
        }
        size_t i0 = ((size_t)(b * CH + dg * 4 + 0)) * NVOX + n;
        size_t i1 = ((size_t)(b * CH + dg * 4 + 1)) * NVOX + n;
        size_t i2 = ((size_t)(b * CH + dg * 4 + 2)) * NVOX + n;
        size_t i3 = ((size_t)(b * CH + dg * 4 + 3)) * NVOX + n;
        out[i0] = a0 + x[i0];
        out[i1] = a1 + x[i1];
        out[i2] = a2 + x[i2];
        out[i3] = a3 + x[i3];
    }
}

// ---------------------------------------------------------------------------
extern "C" void kernel_launch(void* const* d_in, const int* in_sizes, int n_in,
                              void* d_out, int out_size, void* d_ws, size_t ws_size,
                              hipStream_t stream) {
    const float* x     = (const float*)d_in[0];
    const float* gw    = (const float*)d_in[1];
    const float* gb    = (const float*)d_in[2];
    const float* Wqkv  = (const float*)d_in[3];
    const float* Wout  = (const float*)d_in[4];
    const float* obias = (const float*)d_in[5];
    float* out = (float*)d_out;

    float* ws    = (float*)d_ws;
    float* stats = ws;                                     // 256 floats
    unsigned short* Qb = (unsigned short*)(ws + 256);      // 2 MB each
    unsigned short* Kb = Qb + (size_t)BATCH * NVOX * 64;
    unsigned short* Vb = Kb + (size_t)BATCH * NVOX * 64;

    k_gnstats   <<<BATCH * NGRP, 256, 0, stream>>>(x, stats);
    k_qkv       <<<BATCH * 64,   256, 0, stream>>>(x, stats, gw, gb, Wqkv, Qb, Kb, Vb);
    k_attn_fused<<<BATCH * 256,  256, 0, stream>>>(Qb, Kb, Vb, Wout, obias, x, out);
}

// Round 15
// 159.613 us; speedup vs baseline: 1.4392x; 1.4392x over previous
//
#include <hip/hip_runtime.h>
#include <hip/hip_bf16.h>
#include <math.h>

// Problem constants (B=4, C=64, H=W=L=16)
#define BATCH 4
#define CH    64
#define NVOX  4096
#define NGRP  32
#define EPS   1e-5f
#define SPLITS 4
#define KVS   (NVOX / SPLITS)   // 1024 KV per split

typedef float f32x4 __attribute__((ext_vector_type(4)));
typedef short s16x8 __attribute__((ext_vector_type(8)));
typedef unsigned short u16x4 __attribute__((ext_vector_type(4)));

static __device__ inline unsigned short f2bf(float f) {
    union { __hip_bfloat16 h; unsigned short u; } cv;
    cv.h = __float2bfloat16(f);
    return cv.u;
}

// ---------------------------------------------------------------------------
// Kernel 1: GroupNorm statistics. One block per (b, g): 8192 elements.
// ---------------------------------------------------------------------------
__global__ __launch_bounds__(256) void k_gnstats(const float* __restrict__ x,
                                                 float* __restrict__ stats) {
    int bg = blockIdx.x;                       // b*32 + g
    const float4* p4 = (const float4*)(x + (size_t)bg * (2 * NVOX));
    float s = 0.f, sq = 0.f;
    for (int i = threadIdx.x; i < (2 * NVOX) / 4; i += 256) {
        float4 v = p4[i];
        s  += v.x + v.y + v.z + v.w;
        sq += v.x * v.x + v.y * v.y + v.z * v.z + v.w * v.w;
    }
    for (int off = 32; off; off >>= 1) {
        s  += __shfl_down(s, off);
        sq += __shfl_down(sq, off);
    }
    __shared__ float ls[4], lq[4];
    int wid = threadIdx.x >> 6;
    if ((threadIdx.x & 63) == 0) { ls[wid] = s; lq[wid] = sq; }
    __syncthreads();
    if (threadIdx.x == 0) {
        s  = ls[0] + ls[1] + ls[2] + ls[3];
        sq = lq[0] + lq[1] + lq[2] + lq[3];
        float mean = s / (float)(2 * NVOX);
        float var  = sq / (float)(2 * NVOX) - mean * mean;
        stats[bg]       = mean;
        stats[128 + bg] = rsqrtf(var + EPS);
    }
}

// ---------------------------------------------------------------------------
// Kernel 2: MFMA-based normalize + QKV projection.
// Per block (b, 64-n tile): W -> bf16 LDS [192][72]; normalized x tile
// transposed to LDS [n][c] bf16; 4 waves x (Q,K,V d-tile w) x 4 n-tiles x
// 2 K-step MFMAs. Fragment maps identical to the attn-verified ones:
//   A row = lane&15 (d), B col = lane&15 (n), D: col=lane&15, row=g4*4+reg.
// Outputs: Qb/Kb [B][N][64] bf16 (Q pre-scaled 0.125), Vb [B][64][N] bf16.
// ---------------------------------------------------------------------------
__global__ __launch_bounds__(256) void k_qkv(const float* __restrict__ x,
                                             const float* __restrict__ stats,
                                             const float* __restrict__ gw,
                                             const float* __restrict__ gb,
                                             const float* __restrict__ W,
                                             unsigned short* __restrict__ Qb,
                                             unsigned short* __restrict__ Kb,
                                             unsigned short* __restrict__ Vb) {
    int b  = blockIdx.x >> 6;
    int n0 = (blockIdx.x & 63) * 64;
    int t  = threadIdx.x;
    __shared__ alignas(16) unsigned short Wl[192][72];  // [d][c] bf16 +8 pad
    __shared__ alignas(16) unsigned short nt[64][72];   // [n][c] bf16 +8 pad

    // ---- W fp32 -> bf16 LDS (12288 elems, packed 8B stores) ----
    for (int i = t; i < 192 * 16; i += 256) {
        int d  = i >> 4;
        int c4 = (i & 15) * 4;
        float4 v = *(const float4*)&W[d * 64 + c4];
        u16x4 p = { f2bf(v.x), f2bf(v.y), f2bf(v.z), f2bf(v.w) };
        *(u16x4*)&Wl[d][c4] = p;
    }
    // ---- x tile load (coalesced along n) + normalize + transpose to [n][c] ----
    for (int i = t; i < 64 * 16; i += 256) {
        int c  = i >> 4;
        int n4 = (i & 15) * 4;
        float4 v = *(const float4*)&x[((size_t)(b * CH + c)) * NVOX + n0 + n4];
        float mean = stats[b * NGRP + (c >> 1)];
        float rstd = stats[128 + b * NGRP + (c >> 1)];
        float sc = rstd * gw[c];
        float sh = gb[c] - mean * sc;
        nt[n4 + 0][c] = f2bf(v.x * sc + sh);
        nt[n4 + 1][c] = f2bf(v.y * sc + sh);
        nt[n4 + 2][c] = f2bf(v.z * sc + sh);
        nt[n4 + 3][c] = f2bf(v.w * sc + sh);
    }
    __syncthreads();

    int lane = t & 63;
    int w    = t >> 6;          // wave -> d-tile w of each of Q,K,V
    int l15  = lane & 15;
    int g4   = lane >> 4;
    int csl  = g4 * 8;

    // A-fragments: rows d = tile*16 + l15, k-slices csl / csl+32
    s16x8 aQ0 = *(const s16x8*)&Wl[      w * 16 + l15][csl];
    s16x8 aQ1 = *(const s16x8*)&Wl[      w * 16 + l15][csl + 32];
    s16x8 aK0 = *(const s16x8*)&Wl[ 64 + w * 16 + l15][csl];
    s16x8 aK1 = *(const s16x8*)&Wl[ 64 + w * 16 + l15][csl + 32];
    s16x8 aV0 = *(const s16x8*)&Wl[128 + w * 16 + l15][csl];
    s16x8 aV1 = *(const s16x8*)&Wl[128 + w * 16 + l15][csl + 32];

    #pragma unroll
    for (int nti = 0; nti < 4; ++nti) {
        s16x8 b0 = *(const s16x8*)&nt[nti * 16 + l15][csl];
        s16x8 b1 = *(const s16x8*)&nt[nti * 16 + l15][csl + 32];
        f32x4 z = {0.f, 0.f, 0.f, 0.f};
        f32x4 dq = __builtin_amdgcn_mfma_f32_16x16x32_bf16(aQ0, b0, z, 0, 0, 0);
        dq = __builtin_amdgcn_mfma_f32_16x16x32_bf16(aQ1, b1, dq, 0, 0, 0);
        f32x4 dk = __builtin_amdgcn_mfma_f32_16x16x32_bf16(aK0, b0, z, 0, 0, 0);
        dk = __builtin_amdgcn_mfma_f32_16x16x32_bf16(aK1, b1, dk, 0, 0, 0);
        f32x4 dv = __builtin_amdgcn_mfma_f32_16x16x32_bf16(aV0, b0, z, 0, 0, 0);
        dv = __builtin_amdgcn_mfma_f32_16x16x32_bf16(aV1, b1, dv, 0, 0, 0);

        int n = n0 + nti * 16 + l15;        // lane's output column
        // Q (scaled), K: rows d = w*16 + g4*4 + reg are consecutive -> 8B pack
        u16x4 pq = { f2bf(dq[0] * 0.125f), f2bf(dq[1] * 0.125f),
                     f2bf(dq[2] * 0.125f), f2bf(dq[3] * 0.125f) };
        u16x4 pk = { f2bf(dk[0]), f2bf(dk[1]), f2bf(dk[2]), f2bf(dk[3]) };
        size_t qkbase = ((size_t)(b * NVOX + n)) * 64 + w * 16 + g4 * 4;
        *(u16x4*)&Qb[qkbase] = pq;
        *(u16x4*)&Kb[qkbase] = pk;
        // V: c-major rows dv_loc = w*16 + g4*4 + reg
        #pragma unroll
        for (int reg = 0; reg < 4; ++reg)
            Vb[((size_t)(b * 64 + w * 16 + g4 * 4 + reg)) * NVOX + n] = f2bf(dv[reg]);
    }
}

// ---------------------------------------------------------------------------
// Kernel 3: flash attention, bf16 MFMA (16x16x32), KV-split-4.  (round-6
// structure verbatim: LDS-staged K/V, register prefetch, 4 blocks/CU.)
// ---------------------------------------------------------------------------
__global__ __launch_bounds__(256) void k_attn(const unsigned short* __restrict__ Qb,
                                              const unsigned short* __restrict__ Kb,
                                              const unsigned short* __restrict__ Vb,
                                              float* __restrict__ Opart,
                                              float* __restrict__ Mpart,
                                              float* __restrict__ Lpart) {
    int split = blockIdx.x & 3;
    int bq    = blockIdx.x >> 2;
    int b     = bq >> 6;
    int q0    = (bq & 63) * 64;
    int t     = threadIdx.x;
    int lane  = t & 63;
    int w     = t >> 6;
    const int kbase = split * KVS;

    __shared__ alignas(16) unsigned short Ks[64][72];     // [k][c] +8 pad
    __shared__ alignas(16) unsigned short Vs[64][72];     // [c][k] +8 pad
    __shared__ alignas(16) unsigned short Ps[4][16][72];  // per-wave [q][k]

    const unsigned short* Qp = Qb + (size_t)b * NVOX * 64;
    const unsigned short* Kp = Kb + (size_t)b * NVOX * 64;
    const unsigned short* Vp = Vb + (size_t)b * 64 * NVOX;

    int l15 = lane & 15;
    int g4  = lane >> 4;            // 0..3
    int csl = g4 * 8;
    int qrow = q0 + w * 16 + l15;
    s16x8 qf0 = *(const s16x8*)&Qp[(size_t)qrow * 64 + csl];
    s16x8 qf1 = *(const s16x8*)&Qp[(size_t)qrow * 64 + csl + 32];

    f32x4 acc_o[4] = {};            // [c-tile][reg], rows q = g4*4+reg
    float m_r[4], l_r[4];
    #pragma unroll
    for (int i = 0; i < 4; ++i) { m_r[i] = -1e30f; l_r[i] = 0.f; }

    int sr = t >> 2;                // 0..63
    int sc = (t & 3) * 16;          // bf16 col offset

    s16x8 kr0, kr1, vr0, vr1;
    {   // prologue loads (first kv block of this split)
        const s16x8* pk = (const s16x8*)&Kp[((size_t)(kbase + sr)) * 64 + sc];
        kr0 = pk[0]; kr1 = pk[1];
        const s16x8* pv = (const s16x8*)&Vp[(size_t)sr * NVOX + kbase + sc];
        vr0 = pv[0]; vr1 = pv[1];
    }

    for (int it = 0; it < KVS / 64; ++it) {
        *(s16x8*)&Ks[sr][sc]     = kr0;
        *(s16x8*)&Ks[sr][sc + 8] = kr1;
        *(s16x8*)&Vs[sr][sc]     = vr0;
        *(s16x8*)&Vs[sr][sc + 8] = vr1;
        __syncthreads();

        if (it < KVS / 64 - 1) {
            int k0n = kbase + (it + 1) * 64;
            const s16x8* pk = (const s16x8*)&Kp[((size_t)(k0n + sr)) * 64 + sc];
            kr0 = pk[0]; kr1 = pk[1];
            const s16x8* pv = (const s16x8*)&Vp[(size_t)sr * NVOX + k0n + sc];
            vr0 = pv[0]; vr1 = pv[1];
        }

        // ---- S = Q K^T ----
        f32x4 sacc[4];
        #pragma unroll
        for (int kt = 0; kt < 4; ++kt) {
            s16x8 kf0 = *(const s16x8*)&Ks[kt * 16 + l15][csl];
            s16x8 kf1 = *(const s16x8*)&Ks[kt * 16 + l15][csl + 32];
            f32x4 z = {0.f, 0.f, 0.f, 0.f};
            sacc[kt] = __builtin_amdgcn_mfma_f32_16x16x32_bf16(qf0, kf0, z, 0, 0, 0);
            sacc[kt] = __builtin_amdgcn_mfma_f32_16x16x32_bf16(qf1, kf1, sacc[kt], 0, 0, 0);
        }

        // ---- online softmax ----
        float al[4];
        #pragma unroll
        for (int reg = 0; reg < 4; ++reg) {
            float rmax = fmaxf(fmaxf(sacc[0][reg], sacc[1][reg]),
                               fmaxf(sacc[2][reg], sacc[3][reg]));
            rmax = fmaxf(rmax, __shfl_xor(rmax, 1));
            rmax = fmaxf(rmax, __shfl_xor(rmax, 2));
            rmax = fmaxf(rmax, __shfl_xor(rmax, 4));
            rmax = fmaxf(rmax, __shfl_xor(rmax, 8));
            float mn = fmaxf(m_r[reg], rmax);
            al[reg] = __expf(m_r[reg] - mn);
            m_r[reg] = mn;
        }
        float p[4][4];
        #pragma unroll
        for (int kt = 0; kt < 4; ++kt)
            #pragma unroll
            for (int reg = 0; reg < 4; ++reg)
                p[kt][reg] = __expf(sacc[kt][reg] - m_r[reg]);
        #pragma unroll
        for (int reg = 0; reg < 4; ++reg) {
            float rs = p[0][reg] + p[1][reg] + p[2][reg] + p[3][reg];
            rs += __shfl_xor(rs, 1);
            rs += __shfl_xor(rs, 2);
            rs += __shfl_xor(rs, 4);
            rs += __shfl_xor(rs, 8);
            l_r[reg] = l_r[reg] * al[reg] + rs;
        }
        #pragma unroll
        for (int kt = 0; kt < 4; ++kt)
            #pragma unroll
            for (int reg = 0; reg < 4; ++reg)
                Ps[w][g4 * 4 + reg][kt * 16 + l15] = f2bf(p[kt][reg]);
        #pragma unroll
        for (int ct = 0; ct < 4; ++ct)
            #pragma unroll
            for (int reg = 0; reg < 4; ++reg)
                acc_o[ct][reg] *= al[reg];

        // ---- PV ----
        s16x8 pf0 = *(const s16x8*)&Ps[w][l15][csl];
        s16x8 pf1 = *(const s16x8*)&Ps[w][l15][csl + 32];
        #pragma unroll
        for (int ct = 0; ct < 4; ++ct) {
            s16x8 vf0 = *(const s16x8*)&Vs[ct * 16 + l15][csl];
            s16x8 vf1 = *(const s16x8*)&Vs[ct * 16 + l15][csl + 32];
            acc_o[ct] = __builtin_amdgcn_mfma_f32_16x16x32_bf16(pf0, vf0, acc_o[ct], 0, 0, 0);
            acc_o[ct] = __builtin_amdgcn_mfma_f32_16x16x32_bf16(pf1, vf1, acc_o[ct], 0, 0, 0);
        }
        __syncthreads();
    }

    #pragma unroll
    for (int ct = 0; ct < 4; ++ct)
        #pragma unroll
        for (int reg = 0; reg < 4; ++reg) {
            int q = q0 + w * 16 + g4 * 4 + reg;
            Opart[(((size_t)split * BATCH + b) * NVOX + q) * 64 + ct * 16 + l15] =
                acc_o[ct][reg];
        }
    if (l15 == 0) {
        #pragma unroll
        for (int reg = 0; reg < 4; ++reg) {
            int q = q0 + w * 16 + g4 * 4 + reg;
            Mpart[((size_t)split * BATCH + b) * NVOX + q] = m_r[reg];
            Lpart[((size_t)split * BATCH + b) * NVOX + q] = l_r[reg];
        }
    }
}

// ---------------------------------------------------------------------------
// Kernel 4: split-combine + output projection + bias + residual (round-6).
// ---------------------------------------------------------------------------
__global__ __launch_bounds__(256) void k_outproj(const float* __restrict__ Opart,
                                                 const float* __restrict__ Mpart,
                                                 const float* __restrict__ Lpart,
                                                 const float* __restrict__ Wout,
                                                 const float* __restrict__ obias,
                                                 const float* __restrict__ x,
                                                 float* __restrict__ out) {
    int b  = blockIdx.x >> 6;
    int n0 = (blockIdx.x & 63) * 64;
    int t  = threadIdx.x;
    __shared__ float os[64][65];
    __shared__ float scs[64][4];

    if (t < 64) {
        size_t qg = (size_t)b * NVOX + n0 + t;
        float m[SPLITS], l[SPLITS];
        #pragma unroll
        for (int s = 0; s < SPLITS; ++s) {
            m[s] = Mpart[(size_t)s * BATCH * NVOX + qg];
            l[s] = Lpart[(size_t)s * BATCH * NVOX + qg];
        }
        float mm = fmaxf(fmaxf(m[0], m[1]), fmaxf(m[2], m[3]));
        float e[SPLITS], lsum = 0.f;
        #pragma unroll
        for (int s = 0; s < SPLITS; ++s) { e[s] = __expf(m[s] - mm); lsum += l[s] * e[s]; }
        float inv = 1.f / lsum;
        #pragma unroll
        for (int s = 0; s < SPLITS; ++s) scs[t][s] = e[s] * inv;
    }
    __syncthreads();

    for (int i = t; i < 64 * 16; i += 256) {
        int n  = i >> 4;
        int c4 = (i & 15) * 4;
        size_t base = ((size_t)(b * NVOX + n0 + n)) * 64 + c4;
        float4 a = {0.f, 0.f, 0.f, 0.f};
        #pragma unroll
        for (int s = 0; s < SPLITS; ++s) {
            float4 v = *(const float4*)&Opart[(size_t)s * BATCH * NVOX * 64 + base];
            float f = scs[n][s];
            a.x += f * v.x; a.y += f * v.y; a.z += f * v.z; a.w += f * v.w;
        }
        os[n][c4 + 0] = a.x; os[n][c4 + 1] = a.y;
        os[n][c4 + 2] = a.z; os[n][c4 + 3] = a.w;
    }
    __syncthreads();

    int nl = t & 63;
    int dg = t >> 6;
    float r[64];
    #pragma unroll
    for (int c = 0; c < 64; ++c) r[c] = os[nl][c];
    #pragma unroll 4
    for (int j = 0; j < 16; ++j) {
        int d = dg * 16 + j;
        const float* wv = &Wout[d * 64];
        float acc = obias[d];
        #pragma unroll
        for (int c = 0; c < 64; ++c) acc += wv[c] * r[c];
        size_t idx = ((size_t)(b * CH + d)) * NVOX + n0 + nl;
        out[idx] = acc + x[idx];
    }
}

// ---------------------------------------------------------------------------
extern "C" void kernel_launch(void* const* d_in, const int* in_sizes, int n_in,
                              void* d_out, int out_size, void* d_ws, size_t ws_size,
                              hipStream_t stream) {
    const float* x     = (const float*)d_in[0];
    const float* gw    = (const float*)d_in[1];
    const float* gb    = (const float*)d_in[2];
    const float* Wqkv  = (const float*)d_in[3];
    const float* Wout  = (const float*)d_in[4];
    const float* obias = (const float*)d_in[5];
    float* out = (float*)d_out;

    float* ws    = (float*)d_ws;
    float* stats = ws;                                     // 256 floats
    unsigned short* Qb = (unsigned short*)(ws + 256);      // 2 MB each
    unsigned short* Kb = Qb + (size_t)BATCH * NVOX * 64;
    unsigned short* Vb = Kb + (size_t)BATCH * NVOX * 64;
    float* Opart = (float*)(Vb + (size_t)BATCH * NVOX * 64);      // 16 MB
    float* Mpart = Opart + (size_t)SPLITS * BATCH * NVOX * 64;    // 64 KB
    float* Lpart = Mpart + (size_t)SPLITS * BATCH * NVOX;         // 64 KB

    k_gnstats<<<BATCH * NGRP,        256, 0, stream>>>(x, stats);
    k_qkv   <<<BATCH * 64,           256, 0, stream>>>(x, stats, gw, gb, Wqkv, Qb, Kb, Vb);
    k_attn  <<<BATCH * 64 * SPLITS,  256, 0, stream>>>(Qb, Kb, Vb, Opart, Mpart, Lpart);
    k_outproj<<<BATCH * 64,          256, 0, stream>>>(Opart, Mpart, Lpart, Wout, obias, x, out);
}